// Round 1
// baseline (1350.691 us; speedup 1.0000x reference)
//
#include <hip/hip_runtime.h>
#include <stdint.h>

#define B 4
#define N 16384
#define D 512
#define H 256
#define NROWS (B * N)
#define K_SEL 11468
#define N_TOP 10322
#define N_RAND 1146
#define N_REM (N - N_TOP) /* 6062 */
#define HALF_CNT ((B * N_REM) / 2) /* 12124 */
#define RPB 32

// Monotone float -> uint key (larger float => larger key). No NaNs expected.
__device__ __forceinline__ uint32_t f2key(float x) {
  uint32_t u = __float_as_uint(x);
  return u ^ ((u & 0x80000000u) ? 0xFFFFFFFFu : 0x80000000u);
}

// ---------------- K1: fused gated-attention raw scores ----------------
// Block = 256 threads (thread j = attention column), 32 rows per block.
__global__ __launch_bounds__(256) void score_kernel(
    const float* __restrict__ feat, const float* __restrict__ WV,
    const float* __restrict__ bV, const float* __restrict__ WU,
    const float* __restrict__ bU, const float* __restrict__ watt,
    const float* __restrict__ batt, float* __restrict__ raw) {
  const int j = threadIdx.x;
  const int row0 = blockIdx.x * RPB;
  float accV[RPB], accU[RPB];
#pragma unroll
  for (int r = 0; r < RPB; ++r) { accV[r] = 0.f; accU[r] = 0.f; }
  for (int d = 0; d < D; d += 4) {
    float wv[4], wu[4];
#pragma unroll
    for (int t2 = 0; t2 < 4; ++t2) {
      wv[t2] = WV[(d + t2) * H + j];
      wu[t2] = WU[(d + t2) * H + j];
    }
#pragma unroll
    for (int r = 0; r < RPB; ++r) {
      const float4 xv =
          *reinterpret_cast<const float4*>(feat + (size_t)(row0 + r) * D + d);
      accV[r] = fmaf(xv.x, wv[0], accV[r]);
      accV[r] = fmaf(xv.y, wv[1], accV[r]);
      accV[r] = fmaf(xv.z, wv[2], accV[r]);
      accV[r] = fmaf(xv.w, wv[3], accV[r]);
      accU[r] = fmaf(xv.x, wu[0], accU[r]);
      accU[r] = fmaf(xv.y, wu[1], accU[r]);
      accU[r] = fmaf(xv.z, wu[2], accU[r]);
      accU[r] = fmaf(xv.w, wu[3], accU[r]);
    }
  }
  const float bv = bV[j], bu = bU[j], w = watt[j];
  __shared__ float red[RPB][4];
  const int lane = j & 63, wid = j >> 6;
#pragma unroll
  for (int r = 0; r < RPB; ++r) {
    const float aV = tanhf(accV[r] + bv);
    const float aU = 1.0f / (1.0f + expf(-(accU[r] + bu)));
    float g = aV * aU * w;
    for (int off = 32; off > 0; off >>= 1) g += __shfl_down(g, off, 64);
    if (lane == 0) red[r][wid] = g;
  }
  __syncthreads();
  if (j < RPB) {
    raw[row0 + j] = red[j][0] + red[j][1] + red[j][2] + red[j][3] + batt[0];
  }
}

// ---------------- K2: per-row softmax + top-k threshold (radix select) ----
__global__ __launch_bounds__(256) void stats_kernel(
    const float* __restrict__ raw, float* __restrict__ attn_out,
    uint32_t* __restrict__ stats) {
  const int b = blockIdx.x, t = threadIdx.x;
  const float* r = raw + b * N;
  __shared__ float sred[256];
  __shared__ float sM, sS;
  float m = -3.0e38f;
  for (int i = t; i < N; i += 256) m = fmaxf(m, r[i]);
  sred[t] = m;
  __syncthreads();
  if (t == 0) {
    float mm = sred[0];
    for (int i = 1; i < 256; ++i) mm = fmaxf(mm, sred[i]);
    sM = mm;
  }
  __syncthreads();
  const float M = sM;
  float s = 0.f;
  for (int i = t; i < N; i += 256) s += expf(r[i] - M);
  sred[t] = s;
  __syncthreads();
  if (t == 0) {
    float ss = 0.f;
    for (int i = 0; i < 256; ++i) ss += sred[i];
    sS = ss;
  }
  __syncthreads();
  const float inv = 1.0f / sS;
  for (int i = t; i < N; i += 256) attn_out[b * N + i] = expf(r[i] - M) * inv;

  // radix select: key of the N_TOP-th largest element + stable tie count
  __shared__ uint32_t hist[256];
  __shared__ uint32_t sh_prefix;
  __shared__ int sh_rk;
  uint32_t prefix = 0;
  int rk = N_TOP;
  for (int pass = 3; pass >= 0; --pass) {
    const int sh = pass * 8;
    hist[t] = 0;
    __syncthreads();
    for (int i = t; i < N; i += 256) {
      const uint32_t key = f2key(r[i]);
      if (pass == 3 || (key >> (sh + 8)) == (prefix >> (sh + 8)))
        atomicAdd(&hist[(key >> sh) & 255], 1u);
    }
    __syncthreads();
    if (t == 0) {
      int cum = 0, dsel = 0;
      for (int dgt = 255; dgt >= 0; --dgt) {
        const int h = (int)hist[dgt];
        if (cum + h >= rk) { dsel = dgt; break; }
        cum += h;
      }
      sh_prefix = prefix | ((uint32_t)dsel << sh);
      sh_rk = rk - cum;
    }
    __syncthreads();
    prefix = sh_prefix;
    rk = sh_rk;
    __syncthreads();
  }
  if (t == 0) {
    stats[b * 2] = prefix;        // threshold key T
    stats[b * 2 + 1] = (uint32_t)rk; // # of ==T taken (lowest indices first)
  }
}

// ---------------- K3: top-k membership flags + "remaining" list ----------
__global__ __launch_bounds__(256) void topsel_kernel(
    const float* __restrict__ raw, const uint32_t* __restrict__ stats,
    int* __restrict__ flags, int* __restrict__ remaining) {
  const int b = blockIdx.x, t = threadIdx.x;
  const float* r = raw + b * N;
  const uint32_t T = stats[b * 2];
  const int tieTake = (int)stats[b * 2 + 1];
  const int n0 = t * 64;
  int cm = 0, ce = 0;
  for (int i = 0; i < 64; ++i) {
    const uint32_t key = f2key(r[n0 + i]);
    cm += (key > T);
    ce += (key == T);
  }
  __shared__ int s_cm[256], s_ce[256];
  s_cm[t] = cm;
  s_ce[t] = ce;
  __syncthreads();
  if (t == 0) {
    int rm = 0, re = 0;
    for (int i = 0; i < 256; ++i) {
      const int a = s_cm[i], e = s_ce[i];
      s_cm[i] = rm;
      s_ce[i] = re;
      rm += a;
      re += e;
    }
  }
  __syncthreads();
  int gm = s_cm[t], ge = s_ce[t];
  for (int i = 0; i < 64; ++i) {
    const int n = n0 + i;
    const uint32_t key = f2key(r[n]);
    bool mem;
    if (key > T) mem = true;
    else if (key == T) mem = (ge < tieTake);
    else mem = false;
    const int membersBefore = gm + (ge < tieTake ? ge : tieTake);
    if (mem) {
      flags[b * N + n] = 1;
    } else {
      flags[b * N + n] = 0;
      remaining[b * N_REM + (n - membersBefore)] = n;
    }
    gm += (key > T);
    ge += (key == T);
  }
}

// ---------------- K4: Threefry scores + pick N_RAND smallest --------------
__device__ __forceinline__ void threefry(uint32_t x0, uint32_t x1,
                                         uint32_t& o0, uint32_t& o1) {
  const uint32_t k0 = 0u, k1 = 42u;
  const uint32_t ks[3] = {k0, k1, k0 ^ k1 ^ 0x1BD11BDAu};
  x0 += ks[0];
  x1 += ks[1];
  const int R0[4] = {13, 15, 26, 6}, R1[4] = {17, 29, 16, 24};
#pragma unroll
  for (int i = 0; i < 5; ++i) {
    const int* R = (i & 1) ? R1 : R0;
#pragma unroll
    for (int jr = 0; jr < 4; ++jr) {
      x0 += x1;
      x1 = (x1 << R[jr]) | (x1 >> (32 - R[jr]));
      x1 ^= x0;
    }
    x0 += ks[(i + 1) % 3];
    x1 += ks[(i + 2) % 3] + (uint32_t)(i + 1);
  }
  o0 = x0;
  o1 = x1;
}

__global__ __launch_bounds__(256) void rand_kernel(
    const int* __restrict__ remaining, int* __restrict__ flags) {
  const int b = blockIdx.x, t = threadIdx.x;
  __shared__ uint32_t skey[N_REM];
  for (int p = t; p < N_REM; p += 256) {
    const int f = b * N_REM + p;
    uint32_t o0, o1, bits;
    if (f < HALF_CNT) {
      threefry((uint32_t)f, (uint32_t)(f + HALF_CNT), o0, o1);
      bits = o0;
    } else {
      threefry((uint32_t)(f - HALF_CNT), (uint32_t)f, o0, o1);
      bits = o1;
    }
    const float u = __uint_as_float((bits >> 9) | 0x3f800000u) - 1.0f;
    skey[p] = f2key(u);
  }
  __syncthreads();
  __shared__ uint32_t hist[256];
  __shared__ uint32_t sh_prefix;
  __shared__ int sh_rk;
  uint32_t prefix = 0;
  int rk = N_RAND;
  for (int pass = 3; pass >= 0; --pass) {
    const int sh = pass * 8;
    hist[t] = 0;
    __syncthreads();
    for (int p = t; p < N_REM; p += 256) {
      const uint32_t key = skey[p];
      if (pass == 3 || (key >> (sh + 8)) == (prefix >> (sh + 8)))
        atomicAdd(&hist[(key >> sh) & 255], 1u);
    }
    __syncthreads();
    if (t == 0) {
      int cum = 0, dsel = 0;
      for (int dgt = 0; dgt < 256; ++dgt) {
        const int h = (int)hist[dgt];
        if (cum + h >= rk) { dsel = dgt; break; }
        cum += h;
      }
      sh_prefix = prefix | ((uint32_t)dsel << sh);
      sh_rk = rk - cum;
    }
    __syncthreads();
    prefix = sh_prefix;
    rk = sh_rk;
    __syncthreads();
  }
  // stable mark: all keys < T2, plus first rk ties in ascending p order
  const int CH = 24; // 256*24 >= 6062
  const int p0 = t * CH;
  const int pe = (p0 + CH < N_REM) ? p0 + CH : N_REM;
  int ce = 0;
  for (int p = p0; p < pe; ++p) ce += (skey[p] == prefix);
  __shared__ int s_ce[256];
  s_ce[t] = ce;
  __syncthreads();
  if (t == 0) {
    int run = 0;
    for (int i = 0; i < 256; ++i) {
      const int a = s_ce[i];
      s_ce[i] = run;
      run += a;
    }
  }
  __syncthreads();
  int ge = s_ce[t];
  for (int p = p0; p < pe; ++p) {
    const uint32_t key = skey[p];
    const bool pick = (key < prefix) || (key == prefix && ge < rk);
    ge += (key == prefix);
    if (pick) flags[b * N + remaining[b * N_REM + p]] = 1;
  }
}

// ---------------- K5: ordered compaction -> sel_idx ----------------------
__global__ __launch_bounds__(256) void compact_kernel(
    const int* __restrict__ flags, int* __restrict__ sel_ws,
    float* __restrict__ out_selidx) {
  const int b = blockIdx.x, t = threadIdx.x;
  const int n0 = t * 64;
  int c = 0;
  for (int i = 0; i < 64; ++i) c += flags[b * N + n0 + i];
  __shared__ int s_c[256];
  s_c[t] = c;
  __syncthreads();
  if (t == 0) {
    int run = 0;
    for (int i = 0; i < 256; ++i) {
      const int a = s_c[i];
      s_c[i] = run;
      run += a;
    }
  }
  __syncthreads();
  int q = s_c[t];
  for (int i = 0; i < 64; ++i) {
    const int n = n0 + i;
    if (flags[b * N + n]) {
      sel_ws[b * K_SEL + q] = n;
      out_selidx[b * K_SEL + q] = (float)n;
      ++q;
    }
  }
}

// ---------------- K6: gather selected feature rows ------------------------
__global__ __launch_bounds__(128) void gather_kernel(
    const float* __restrict__ feat, const int* __restrict__ sel_ws,
    float* __restrict__ out_sel) {
  const int qa = blockIdx.x;
  const int b = qa / K_SEL;
  const int n = sel_ws[qa];
  const float4* src =
      reinterpret_cast<const float4*>(feat + (size_t)(b * N + n) * D);
  float4* dst = reinterpret_cast<float4*>(out_sel + (size_t)qa * D);
  dst[threadIdx.x] = src[threadIdx.x];
}

extern "C" void kernel_launch(void* const* d_in, const int* in_sizes, int n_in,
                              void* d_out, int out_size, void* d_ws,
                              size_t ws_size, hipStream_t stream) {
  const float* feat = (const float*)d_in[0];
  const float* WV = (const float*)d_in[1];
  const float* bV = (const float*)d_in[2];
  const float* WU = (const float*)d_in[3];
  const float* bU = (const float*)d_in[4];
  const float* watt = (const float*)d_in[5];
  const float* batt = (const float*)d_in[6];

  float* out = (float*)d_out;
  float* out_selected = out;                          // B*K_SEL*D floats
  float* out_attn = out + (size_t)B * K_SEL * D;      // B*N floats
  float* out_selidx = out_attn + (size_t)B * N;       // B*K_SEL floats

  float* raw = (float*)d_ws;                    // NROWS floats
  uint32_t* stats = (uint32_t*)(raw + NROWS);   // B*2
  int* remaining = (int*)(stats + B * 2);       // B*N_REM
  int* flags = remaining + B * N_REM;           // NROWS
  int* sel_ws = flags + NROWS;                  // B*K_SEL

  score_kernel<<<NROWS / RPB, 256, 0, stream>>>(feat, WV, bV, WU, bU, watt,
                                                batt, raw);
  stats_kernel<<<B, 256, 0, stream>>>(raw, out_attn, stats);
  topsel_kernel<<<B, 256, 0, stream>>>(raw, stats, flags, remaining);
  rand_kernel<<<B, 256, 0, stream>>>(remaining, flags);
  compact_kernel<<<B, 256, 0, stream>>>(flags, sel_ws, out_selidx);
  gather_kernel<<<B * K_SEL, 128, 0, stream>>>(feat, sel_ws, out_selected);
}

// Round 2
// 859.830 us; speedup vs baseline: 1.5709x; 1.5709x over previous
//
#include <hip/hip_runtime.h>
#include <stdint.h>

#define B 4
#define N 16384
#define D 512
#define H 256
#define NROWS (B * N)
#define K_SEL 11468
#define N_TOP 10322
#define N_RAND 1146
#define N_REM (N - N_TOP) /* 6062 */
#define HALF_CNT ((B * N_REM) / 2) /* 12124 */

typedef float v2f __attribute__((ext_vector_type(2)));
typedef float v4f __attribute__((ext_vector_type(4)));

// acc.(lo,hi) += (x.lo, x.lo) * (w.lo, w.hi)
#define PK_LO(acc, x, w)                                           \
  asm("v_pk_fma_f32 %0, %1, %2, %0 op_sel_hi:[0,1,1]"              \
      : "+v"(acc)                                                  \
      : "v"(x), "v"(w))
// acc.(lo,hi) += (x.hi, x.hi) * (w.lo, w.hi)
#define PK_HI(acc, x, w)                                           \
  asm("v_pk_fma_f32 %0, %1, %2, %0 op_sel:[1,0,0] op_sel_hi:[1,1,1]" \
      : "+v"(acc)                                                  \
      : "v"(x), "v"(w))

// Monotone float -> uint key (larger float => larger key). No NaNs expected.
__device__ __forceinline__ uint32_t f2key(float x) {
  uint32_t u = __float_as_uint(x);
  return u ^ ((u & 0x80000000u) ? 0xFFFFFFFFu : 0x80000000u);
}

// ---------------- K0: interleave weights: wcat[k][2j]=(WV[k][j],WU[k][j]) --
__global__ __launch_bounds__(256) void wprep_kernel(
    const float* __restrict__ WV, const float* __restrict__ WU,
    float* __restrict__ wcat) {
  const int k = blockIdx.x;   // 0..511
  const int j = threadIdx.x;  // 0..255
  v2f p;
  p.x = WV[k * H + j];
  p.y = WU[k * H + j];
  *reinterpret_cast<v2f*>(&wcat[(size_t)k * 2 * H + 2 * j]) = p;
}

// ---------------- K1: fused gated-attention raw scores --------------------
// Block 256 threads: tid&127 = col j (handles j and j+128), tid>>7 = row half.
// Block covers 32 rows; features staged in LDS per 128-k tile; V/U packed in
// one v2f accumulator driven by v_pk_fma_f32 with op_sel feature broadcast.
// NOTE: k-summation order, tanh/sigmoid expressions and reduction-tree order
// are bit-identical to the R1 scalar kernel -> `raw` is bit-identical.
__global__ __launch_bounds__(256) void score_kernel(
    const float* __restrict__ feat, const float* __restrict__ wcat,
    const float* __restrict__ bV, const float* __restrict__ bU,
    const float* __restrict__ watt, const float* __restrict__ batt,
    float* __restrict__ raw) {
  __shared__ float lds[32 * 128];  // 16 KB feature tile: 32 rows x 128 k
  const int tid = threadIdx.x;
  const int j = tid & 127;
  const int half = tid >> 7;
  const int row0 = blockIdx.x * 32;

  v2f acc[16][2];
#pragma unroll
  for (int r = 0; r < 16; ++r) {
    acc[r][0] = v2f{0.f, 0.f};
    acc[r][1] = v2f{0.f, 0.f};
  }

  for (int kt = 0; kt < D; kt += 128) {
    __syncthreads();
// stage 32x128 tile: 1024 float4 quads, thread t takes quads t+256*i
#pragma unroll
    for (int i = 0; i < 4; ++i) {
      const int f = tid + 256 * i;
      const int rr = f >> 5;  // 32 quads per row
      const int qq = f & 31;
      *reinterpret_cast<v4f*>(&lds[rr * 128 + qq * 4]) =
          *reinterpret_cast<const v4f*>(
              &feat[(size_t)(row0 + rr) * D + kt + qq * 4]);
    }
    __syncthreads();
    const float* xb = &lds[half * 16 * 128];
    for (int dk = 0; dk < 128; dk += 4) {
      const float* wr0 = &wcat[(size_t)(kt + dk) * 512 + 2 * j];
      const v2f w0a = *reinterpret_cast<const v2f*>(wr0);
      const v2f w0b = *reinterpret_cast<const v2f*>(wr0 + 256);
      const v2f w1a = *reinterpret_cast<const v2f*>(wr0 + 512);
      const v2f w1b = *reinterpret_cast<const v2f*>(wr0 + 512 + 256);
      const v2f w2a = *reinterpret_cast<const v2f*>(wr0 + 1024);
      const v2f w2b = *reinterpret_cast<const v2f*>(wr0 + 1024 + 256);
      const v2f w3a = *reinterpret_cast<const v2f*>(wr0 + 1536);
      const v2f w3b = *reinterpret_cast<const v2f*>(wr0 + 1536 + 256);
#pragma unroll
      for (int r = 0; r < 16; ++r) {
        const v2f x01 = *reinterpret_cast<const v2f*>(&xb[r * 128 + dk]);
        const v2f x23 = *reinterpret_cast<const v2f*>(&xb[r * 128 + dk + 2]);
        PK_LO(acc[r][0], x01, w0a);
        PK_HI(acc[r][0], x01, w1a);
        PK_LO(acc[r][0], x23, w2a);
        PK_HI(acc[r][0], x23, w3a);
        PK_LO(acc[r][1], x01, w0b);
        PK_HI(acc[r][1], x01, w1b);
        PK_LO(acc[r][1], x23, w2b);
        PK_HI(acc[r][1], x23, w3b);
      }
    }
  }

  // epilogue: g = tanh(V+bv)*sigmoid(U+bu)*w, reduce 256 cols per row
  const float bv[2] = {bV[j], bV[j + 128]};
  const float bu[2] = {bU[j], bU[j + 128]};
  const float wa[2] = {watt[j], watt[j + 128]};
  __shared__ float red[32][4];
  const int lane = tid & 63;
  const int wv_id = (tid >> 6) & 1;  // wave within row-group
#pragma unroll
  for (int r = 0; r < 16; ++r) {
#pragma unroll
    for (int c = 0; c < 2; ++c) {
      const float aV = tanhf(acc[r][c].x + bv[c]);
      const float aU = 1.0f / (1.0f + expf(-(acc[r][c].y + bu[c])));
      float g = aV * aU * wa[c];
      for (int off = 32; off > 0; off >>= 1) g += __shfl_down(g, off, 64);
      if (lane == 0) red[half * 16 + r][c * 2 + wv_id] = g;
    }
  }
  __syncthreads();
  if (tid < 32)
    raw[row0 + tid] =
        red[tid][0] + red[tid][1] + red[tid][2] + red[tid][3] + batt[0];
}

// ---------------- K2: per-row softmax + top-k threshold (radix select) ----
__global__ __launch_bounds__(256) void stats_kernel(
    const float* __restrict__ raw, float* __restrict__ attn_out,
    uint32_t* __restrict__ stats) {
  const int b = blockIdx.x, t = threadIdx.x;
  const float* r = raw + b * N;
  __shared__ float sred[256];
  __shared__ float sM, sS;
  float m = -3.0e38f;
  for (int i = t; i < N; i += 256) m = fmaxf(m, r[i]);
  sred[t] = m;
  __syncthreads();
  if (t == 0) {
    float mm = sred[0];
    for (int i = 1; i < 256; ++i) mm = fmaxf(mm, sred[i]);
    sM = mm;
  }
  __syncthreads();
  const float M = sM;
  float s = 0.f;
  for (int i = t; i < N; i += 256) s += expf(r[i] - M);
  sred[t] = s;
  __syncthreads();
  if (t == 0) {
    float ss = 0.f;
    for (int i = 0; i < 256; ++i) ss += sred[i];
    sS = ss;
  }
  __syncthreads();
  const float inv = 1.0f / sS;
  for (int i = t; i < N; i += 256) attn_out[b * N + i] = expf(r[i] - M) * inv;

  // radix select: key of the N_TOP-th largest element + stable tie count
  __shared__ uint32_t hist[256];
  __shared__ uint32_t sh_prefix;
  __shared__ int sh_rk;
  uint32_t prefix = 0;
  int rk = N_TOP;
  for (int pass = 3; pass >= 0; --pass) {
    const int sh = pass * 8;
    hist[t] = 0;
    __syncthreads();
    for (int i = t; i < N; i += 256) {
      const uint32_t key = f2key(r[i]);
      if (pass == 3 || (key >> (sh + 8)) == (prefix >> (sh + 8)))
        atomicAdd(&hist[(key >> sh) & 255], 1u);
    }
    __syncthreads();
    if (t == 0) {
      int cum = 0, dsel = 0;
      for (int dgt = 255; dgt >= 0; --dgt) {
        const int h = (int)hist[dgt];
        if (cum + h >= rk) { dsel = dgt; break; }
        cum += h;
      }
      sh_prefix = prefix | ((uint32_t)dsel << sh);
      sh_rk = rk - cum;
    }
    __syncthreads();
    prefix = sh_prefix;
    rk = sh_rk;
    __syncthreads();
  }
  if (t == 0) {
    stats[b * 2] = prefix;           // threshold key T
    stats[b * 2 + 1] = (uint32_t)rk; // # of ==T taken (lowest indices first)
  }
}

// ---------------- K3: top-k membership flags + "remaining" list ----------
__global__ __launch_bounds__(256) void topsel_kernel(
    const float* __restrict__ raw, const uint32_t* __restrict__ stats,
    int* __restrict__ flags, int* __restrict__ remaining) {
  const int b = blockIdx.x, t = threadIdx.x;
  const float* r = raw + b * N;
  const uint32_t T = stats[b * 2];
  const int tieTake = (int)stats[b * 2 + 1];
  const int n0 = t * 64;
  int cm = 0, ce = 0;
  for (int i = 0; i < 64; ++i) {
    const uint32_t key = f2key(r[n0 + i]);
    cm += (key > T);
    ce += (key == T);
  }
  __shared__ int s_cm[256], s_ce[256];
  s_cm[t] = cm;
  s_ce[t] = ce;
  __syncthreads();
  if (t == 0) {
    int rm = 0, re = 0;
    for (int i = 0; i < 256; ++i) {
      const int a = s_cm[i], e = s_ce[i];
      s_cm[i] = rm;
      s_ce[i] = re;
      rm += a;
      re += e;
    }
  }
  __syncthreads();
  int gm = s_cm[t], ge = s_ce[t];
  for (int i = 0; i < 64; ++i) {
    const int n = n0 + i;
    const uint32_t key = f2key(r[n]);
    bool mem;
    if (key > T) mem = true;
    else if (key == T) mem = (ge < tieTake);
    else mem = false;
    const int membersBefore = gm + (ge < tieTake ? ge : tieTake);
    if (mem) {
      flags[b * N + n] = 1;
    } else {
      flags[b * N + n] = 0;
      remaining[b * N_REM + (n - membersBefore)] = n;
    }
    gm += (key > T);
    ge += (key == T);
  }
}

// ---------------- K4: Threefry scores + pick N_RAND smallest --------------
__device__ __forceinline__ void threefry(uint32_t x0, uint32_t x1,
                                         uint32_t& o0, uint32_t& o1) {
  const uint32_t k0 = 0u, k1 = 42u;
  const uint32_t ks[3] = {k0, k1, k0 ^ k1 ^ 0x1BD11BDAu};
  x0 += ks[0];
  x1 += ks[1];
  const int R0[4] = {13, 15, 26, 6}, R1[4] = {17, 29, 16, 24};
#pragma unroll
  for (int i = 0; i < 5; ++i) {
    const int* R = (i & 1) ? R1 : R0;
#pragma unroll
    for (int jr = 0; jr < 4; ++jr) {
      x0 += x1;
      x1 = (x1 << R[jr]) | (x1 >> (32 - R[jr]));
      x1 ^= x0;
    }
    x0 += ks[(i + 1) % 3];
    x1 += ks[(i + 2) % 3] + (uint32_t)(i + 1);
  }
  o0 = x0;
  o1 = x1;
}

__global__ __launch_bounds__(256) void rand_kernel(
    const int* __restrict__ remaining, int* __restrict__ flags) {
  const int b = blockIdx.x, t = threadIdx.x;
  __shared__ uint32_t skey[N_REM];
  for (int p = t; p < N_REM; p += 256) {
    const int f = b * N_REM + p;
    uint32_t o0, o1, bits;
    if (f < HALF_CNT) {
      threefry((uint32_t)f, (uint32_t)(f + HALF_CNT), o0, o1);
      bits = o0;
    } else {
      threefry((uint32_t)(f - HALF_CNT), (uint32_t)f, o0, o1);
      bits = o1;
    }
    const float u = __uint_as_float((bits >> 9) | 0x3f800000u) - 1.0f;
    skey[p] = f2key(u);
  }
  __syncthreads();
  __shared__ uint32_t hist[256];
  __shared__ uint32_t sh_prefix;
  __shared__ int sh_rk;
  uint32_t prefix = 0;
  int rk = N_RAND;
  for (int pass = 3; pass >= 0; --pass) {
    const int sh = pass * 8;
    hist[t] = 0;
    __syncthreads();
    for (int p = t; p < N_REM; p += 256) {
      const uint32_t key = skey[p];
      if (pass == 3 || (key >> (sh + 8)) == (prefix >> (sh + 8)))
        atomicAdd(&hist[(key >> sh) & 255], 1u);
    }
    __syncthreads();
    if (t == 0) {
      int cum = 0, dsel = 0;
      for (int dgt = 0; dgt < 256; ++dgt) {
        const int h = (int)hist[dgt];
        if (cum + h >= rk) { dsel = dgt; break; }
        cum += h;
      }
      sh_prefix = prefix | ((uint32_t)dsel << sh);
      sh_rk = rk - cum;
    }
    __syncthreads();
    prefix = sh_prefix;
    rk = sh_rk;
    __syncthreads();
  }
  // stable mark: all keys < T2, plus first rk ties in ascending p order
  const int CH = 24;  // 256*24 >= 6062
  const int p0 = t * CH;
  const int pe = (p0 + CH < N_REM) ? p0 + CH : N_REM;
  int ce = 0;
  for (int p = p0; p < pe; ++p) ce += (skey[p] == prefix);
  __shared__ int s_ce[256];
  s_ce[t] = ce;
  __syncthreads();
  if (t == 0) {
    int run = 0;
    for (int i = 0; i < 256; ++i) {
      const int a = s_ce[i];
      s_ce[i] = run;
      run += a;
    }
  }
  __syncthreads();
  int ge = s_ce[t];
  for (int p = p0; p < pe; ++p) {
    const uint32_t key = skey[p];
    const bool pick = (key < prefix) || (key == prefix && ge < rk);
    ge += (key == prefix);
    if (pick) flags[b * N + remaining[b * N_REM + p]] = 1;
  }
}

// ---------------- K5: ordered compaction -> sel_idx ----------------------
__global__ __launch_bounds__(256) void compact_kernel(
    const int* __restrict__ flags, int* __restrict__ sel_ws,
    float* __restrict__ out_selidx) {
  const int b = blockIdx.x, t = threadIdx.x;
  const int n0 = t * 64;
  int c = 0;
  for (int i = 0; i < 64; ++i) c += flags[b * N + n0 + i];
  __shared__ int s_c[256];
  s_c[t] = c;
  __syncthreads();
  if (t == 0) {
    int run = 0;
    for (int i = 0; i < 256; ++i) {
      const int a = s_c[i];
      s_c[i] = run;
      run += a;
    }
  }
  __syncthreads();
  int q = s_c[t];
  for (int i = 0; i < 64; ++i) {
    const int n = n0 + i;
    if (flags[b * N + n]) {
      sel_ws[b * K_SEL + q] = n;
      out_selidx[b * K_SEL + q] = (float)n;
      ++q;
    }
  }
}

// ---------------- K6: gather selected feature rows ------------------------
__global__ __launch_bounds__(128) void gather_kernel(
    const float* __restrict__ feat, const int* __restrict__ sel_ws,
    float* __restrict__ out_sel) {
  const int qa = blockIdx.x;
  const int b = qa / K_SEL;
  const int n = sel_ws[qa];
  const float4* src =
      reinterpret_cast<const float4*>(feat + (size_t)(b * N + n) * D);
  float4* dst = reinterpret_cast<float4*>(out_sel + (size_t)qa * D);
  dst[threadIdx.x] = src[threadIdx.x];
}

extern "C" void kernel_launch(void* const* d_in, const int* in_sizes, int n_in,
                              void* d_out, int out_size, void* d_ws,
                              size_t ws_size, hipStream_t stream) {
  const float* feat = (const float*)d_in[0];
  const float* WV = (const float*)d_in[1];
  const float* bV = (const float*)d_in[2];
  const float* WU = (const float*)d_in[3];
  const float* bU = (const float*)d_in[4];
  const float* watt = (const float*)d_in[5];
  const float* batt = (const float*)d_in[6];

  float* out = (float*)d_out;
  float* out_selected = out;                      // B*K_SEL*D floats
  float* out_attn = out + (size_t)B * K_SEL * D;  // B*N floats
  float* out_selidx = out_attn + (size_t)B * N;   // B*K_SEL floats

  float* wcat = (float*)d_ws;                   // D*2*H = 524288 floats? no: 512*512
  float* raw = wcat + (size_t)D * 2 * H;        // NROWS floats
  uint32_t* stats = (uint32_t*)(raw + NROWS);   // B*2
  int* remaining = (int*)(stats + B * 2);       // B*N_REM
  int* flags = remaining + B * N_REM;           // NROWS
  int* sel_ws = flags + NROWS;                  // B*K_SEL

  wprep_kernel<<<D, 256, 0, stream>>>(WV, WU, wcat);
  score_kernel<<<NROWS / 32, 256, 0, stream>>>(feat, wcat, bV, bU, watt, batt,
                                               raw);
  stats_kernel<<<B, 256, 0, stream>>>(raw, out_attn, stats);
  topsel_kernel<<<B, 256, 0, stream>>>(raw, stats, flags, remaining);
  rand_kernel<<<B, 256, 0, stream>>>(remaining, flags);
  compact_kernel<<<B, 256, 0, stream>>>(flags, sel_ws, out_selidx);
  gather_kernel<<<B * K_SEL, 128, 0, stream>>>(feat, sel_ws, out_selected);
}

// Round 3
// 758.037 us; speedup vs baseline: 1.7818x; 1.1343x over previous
//
#include <hip/hip_runtime.h>
#include <stdint.h>

#define B 4
#define N 16384
#define D 512
#define H 256
#define NROWS (B * N)
#define K_SEL 11468
#define N_TOP 10322
#define N_RAND 1146
#define N_REM (N - N_TOP) /* 6062 */
#define HALF_CNT ((B * N_REM) / 2) /* 12124 */

typedef float v2f __attribute__((ext_vector_type(2)));
typedef float v4f __attribute__((ext_vector_type(4)));

// acc.(lo,hi) += (xs.lo, xs.lo) * (w.lo, w.hi)   [xs = SGPR pair]
#define PKS_LO(acc, xs, w)                                             \
  asm("v_pk_fma_f32 %0, %1, %2, %0 op_sel_hi:[0,1,1]"                  \
      : "+v"(acc)                                                      \
      : "s"(xs), "v"(w))
// acc.(lo,hi) += (xs.hi, xs.hi) * (w.lo, w.hi)
#define PKS_HI(acc, xs, w)                                             \
  asm("v_pk_fma_f32 %0, %1, %2, %0 op_sel:[1,0,0] op_sel_hi:[1,1,1]"   \
      : "+v"(acc)                                                      \
      : "s"(xs), "v"(w))

// Monotone float -> uint key (larger float => larger key). No NaNs expected.
__device__ __forceinline__ uint32_t f2key(float x) {
  uint32_t u = __float_as_uint(x);
  return u ^ ((u & 0x80000000u) ? 0xFFFFFFFFu : 0x80000000u);
}

// ---- K0: weight quads: wq[(k2*256+j)*4] = {WV[2k2][j],WU[2k2][j],WV[2k2+1][j],WU[2k2+1][j]}
__global__ __launch_bounds__(256) void wprep_kernel(
    const float* __restrict__ WV, const float* __restrict__ WU,
    float* __restrict__ wqf) {
  const int k2 = blockIdx.x;  // 0..255
  const int j = threadIdx.x;  // 0..255
  v4f p;
  p.x = WV[(2 * k2) * H + j];
  p.y = WU[(2 * k2) * H + j];
  p.z = WV[(2 * k2 + 1) * H + j];
  p.w = WU[(2 * k2 + 1) * H + j];
  *(reinterpret_cast<v4f*>(wqf) + (k2 * H + j)) = p;
}

// ---- K1: fused gated-attention raw scores. 2048 blocks x 256 thr (4 waves).
// wave = (rg = rowgroup of 16 rows, ch = col half). lane covers cols
// j1=ch*128+lane, j2=j1+64. x via s_load (SGPR), w via global dwordx4 (VGPR).
// k-order / activation / reduction order bit-identical to the R2 kernel.
__global__ __launch_bounds__(256) void score_kernel(
    const float* __restrict__ feat, const float* __restrict__ wqf,
    const float* __restrict__ bV, const float* __restrict__ bU,
    const float* __restrict__ watt, const float* __restrict__ batt,
    float* __restrict__ raw) {
  const int tid = threadIdx.x;
  const int lane = tid & 63;
  const int wv4 = __builtin_amdgcn_readfirstlane(tid >> 6);
  const int rg = wv4 >> 1, ch = wv4 & 1;
  const int j1 = ch * 128 + lane;
  const int j2 = j1 + 64;
  const int row0 = blockIdx.x * 32 + rg * 16;
  const float* rowbase = feat + (size_t)row0 * D;  // uniform -> SGPR pair
  const v4f* w1p = reinterpret_cast<const v4f*>(wqf) + j1;
  const v4f* w2p = reinterpret_cast<const v4f*>(wqf) + j2;

  v2f acc[16][2];
#pragma unroll
  for (int r = 0; r < 16; ++r) {
    acc[r][0] = v2f{0.f, 0.f};
    acc[r][1] = v2f{0.f, 0.f};
  }

  for (int kt = 0; kt < D; kt += 4) {
    const int so = kt * 4;  // byte soffset within a row
    v4f X0, X1, X2, X3, X4, X5, X6, X7, X8, X9, X10, X11, X12, X13, X14, X15;
#define SLOAD(i)                                                        \
  {                                                                     \
    const int soR = so + (i)*2048;                                      \
    asm("s_load_dwordx4 %0, %1, %2" : "=s"(X##i) : "s"(rowbase), "s"(soR)); \
  }
    SLOAD(0) SLOAD(1) SLOAD(2) SLOAD(3) SLOAD(4) SLOAD(5) SLOAD(6) SLOAD(7)
    SLOAD(8) SLOAD(9) SLOAD(10) SLOAD(11) SLOAD(12) SLOAD(13) SLOAD(14)
    SLOAD(15)
#undef SLOAD

    const size_t k2i = (size_t)(kt >> 1) * 256;
    const v4f wA = w1p[k2i];
    const v4f wB = w1p[k2i + 256];
    const v4f wC = w2p[k2i];
    const v4f wD = w2p[k2i + 256];
    const v2f wA01 = __builtin_shufflevector(wA, wA, 0, 1);
    const v2f wA23 = __builtin_shufflevector(wA, wA, 2, 3);
    const v2f wB01 = __builtin_shufflevector(wB, wB, 0, 1);
    const v2f wB23 = __builtin_shufflevector(wB, wB, 2, 3);
    const v2f wC01 = __builtin_shufflevector(wC, wC, 0, 1);
    const v2f wC23 = __builtin_shufflevector(wC, wC, 2, 3);
    const v2f wD01 = __builtin_shufflevector(wD, wD, 0, 1);
    const v2f wD23 = __builtin_shufflevector(wD, wD, 2, 3);

    // gate: pk consumers below data-depend on X via this asm
    asm("s_waitcnt lgkmcnt(0)"
        : "+s"(X0), "+s"(X1), "+s"(X2), "+s"(X3), "+s"(X4), "+s"(X5),
          "+s"(X6), "+s"(X7), "+s"(X8), "+s"(X9), "+s"(X10), "+s"(X11),
          "+s"(X12), "+s"(X13), "+s"(X14), "+s"(X15));

#define ROW(i)                                                   \
  {                                                              \
    const v2f x01 = __builtin_shufflevector(X##i, X##i, 0, 1);   \
    const v2f x23 = __builtin_shufflevector(X##i, X##i, 2, 3);   \
    PKS_LO(acc[i][0], x01, wA01);                                \
    PKS_HI(acc[i][0], x01, wA23);                                \
    PKS_LO(acc[i][0], x23, wB01);                                \
    PKS_HI(acc[i][0], x23, wB23);                                \
    PKS_LO(acc[i][1], x01, wC01);                                \
    PKS_HI(acc[i][1], x01, wC23);                                \
    PKS_LO(acc[i][1], x23, wD01);                                \
    PKS_HI(acc[i][1], x23, wD23);                                \
  }
    ROW(0) ROW(1) ROW(2) ROW(3) ROW(4) ROW(5) ROW(6) ROW(7)
    ROW(8) ROW(9) ROW(10) ROW(11) ROW(12) ROW(13) ROW(14) ROW(15)
#undef ROW
  }

  // epilogue (bit-identical structure to R2): per (r,c) lane-tree over 64
  // j-consecutive lanes, 4 slots in ascending-j order, then slot0+1+2+3+batt.
  const float bv1 = bV[j1], bu1 = bU[j1], wa1 = watt[j1];
  const float bv2 = bV[j2], bu2 = bU[j2], wa2 = watt[j2];
  __shared__ float red[32][4];
#pragma unroll
  for (int r = 0; r < 16; ++r) {
#pragma unroll
    for (int c = 0; c < 2; ++c) {
      const float bv = c ? bv2 : bv1;
      const float bu = c ? bu2 : bu1;
      const float wa = c ? wa2 : wa1;
      const float aV = tanhf(acc[r][c].x + bv);
      const float aU = 1.0f / (1.0f + expf(-(acc[r][c].y + bu)));
      float g = aV * aU * wa;
      for (int off = 32; off > 0; off >>= 1) g += __shfl_down(g, off, 64);
      if (lane == 0) red[rg * 16 + r][ch * 2 + c] = g;
    }
  }
  __syncthreads();
  if (tid < 32)
    raw[blockIdx.x * 32 + tid] =
        red[tid][0] + red[tid][1] + red[tid][2] + red[tid][3] + batt[0];
}

// ---- K2: Threefry scores + pick N_RAND smallest positions -> psel bitmap --
__device__ __forceinline__ void threefry(uint32_t x0, uint32_t x1,
                                         uint32_t& o0, uint32_t& o1) {
  const uint32_t k0 = 0u, k1 = 42u;
  const uint32_t ks[3] = {k0, k1, k0 ^ k1 ^ 0x1BD11BDAu};
  x0 += ks[0];
  x1 += ks[1];
  const int R0[4] = {13, 15, 26, 6}, R1[4] = {17, 29, 16, 24};
#pragma unroll
  for (int i = 0; i < 5; ++i) {
    const int* R = (i & 1) ? R1 : R0;
#pragma unroll
    for (int jr = 0; jr < 4; ++jr) {
      x0 += x1;
      x1 = (x1 << R[jr]) | (x1 >> (32 - R[jr]));
      x1 ^= x0;
    }
    x0 += ks[(i + 1) % 3];
    x1 += ks[(i + 2) % 3] + (uint32_t)(i + 1);
  }
  o0 = x0;
  o1 = x1;
}

__global__ __launch_bounds__(1024) void rand_select_kernel(
    int* __restrict__ psel) {
  const int b = blockIdx.x, t = threadIdx.x;
  __shared__ uint32_t skey[N_REM];
  __shared__ uint32_t hist[256];
  __shared__ uint32_t sh_prefix;
  __shared__ int sh_rk;
  __shared__ int s_ce[1024];
  for (int p = t; p < N_REM; p += 1024) {
    psel[b * N_REM + p] = 0;
    const int f = b * N_REM + p;
    uint32_t o0, o1, bits;
    if (f < HALF_CNT) {
      threefry((uint32_t)f, (uint32_t)(f + HALF_CNT), o0, o1);
      bits = o0;
    } else {
      threefry((uint32_t)(f - HALF_CNT), (uint32_t)f, o0, o1);
      bits = o1;
    }
    const float u = __uint_as_float((bits >> 9) | 0x3f800000u) - 1.0f;
    skey[p] = f2key(u);
  }
  __syncthreads();
  uint32_t prefix = 0;
  int rk = N_RAND;
  for (int pass = 3; pass >= 0; --pass) {
    const int sh = pass * 8;
    if (t < 256) hist[t] = 0;
    __syncthreads();
    for (int p = t; p < N_REM; p += 1024) {
      const uint32_t key = skey[p];
      if (pass == 3 || (key >> (sh + 8)) == (prefix >> (sh + 8)))
        atomicAdd(&hist[(key >> sh) & 255], 1u);
    }
    __syncthreads();
    if (t == 0) {
      int cum = 0, dsel = 0;
      for (int dgt = 0; dgt < 256; ++dgt) {
        const int h = (int)hist[dgt];
        if (cum + h >= rk) { dsel = dgt; break; }
        cum += h;
      }
      sh_prefix = prefix | ((uint32_t)dsel << sh);
      sh_rk = rk - cum;
    }
    __syncthreads();
    prefix = sh_prefix;
    rk = sh_rk;
    __syncthreads();
  }
  // stable mark: keys < T, plus first rk ties in ascending p order
  const int CH = 6;  // 1024*6 >= 6062
  const int p0 = t * CH;
  const int pe = (p0 + CH < N_REM) ? p0 + CH : N_REM;
  int ce = 0;
  for (int p = p0; p < pe; ++p) ce += (skey[p] == prefix);
  s_ce[t] = ce;
  __syncthreads();
  if (t == 0) {
    int run = 0;
    for (int i = 0; i < 1024; ++i) {
      const int a = s_ce[i];
      s_ce[i] = run;
      run += a;
    }
  }
  __syncthreads();
  int ge = s_ce[t];
  for (int p = p0; p < pe; ++p) {
    const uint32_t key = skey[p];
    const bool pick = (key < prefix) || (key == prefix && ge < rk);
    ge += (key == prefix);
    if (pick) psel[b * N_REM + p] = 1;
  }
}

// ---- exclusive scan over 1024 per-thread counts --------------------------
__device__ __forceinline__ int scan1024(int c, int* wred, int tid) {
  const int lane = tid & 63, w = tid >> 6;
  int v = c;
#pragma unroll
  for (int off = 1; off < 64; off <<= 1) {
    const int u = __shfl_up(v, off, 64);
    if (lane >= off) v += u;
  }
  if (lane == 63) wred[w] = v;
  __syncthreads();
  if (tid == 0) {
    int run = 0;
    for (int i = 0; i < 16; ++i) {
      const int a = wred[i];
      wred[i] = run;
      run += a;
    }
  }
  __syncthreads();
  const int res = wred[w] + v - c;
  __syncthreads();
  return res;
}

// ---- K3: fused softmax + top-k threshold + membership + compaction -------
__global__ __launch_bounds__(1024) void select_kernel(
    const float* __restrict__ raw, const int* __restrict__ psel,
    float* __restrict__ attn_out, int* __restrict__ sel_ws,
    float* __restrict__ out_selidx) {
  const int b = blockIdx.x, t = threadIdx.x;
  const int lane = t & 63, w = t >> 6;
  __shared__ float sraw[N];        // 64 KB
  __shared__ int whist[16][256];   // 16 KB
  __shared__ int ghist[256];
  __shared__ float fred[16];
  __shared__ int wred[16];
  __shared__ float shM, shS;
  __shared__ uint32_t sh_prefix;
  __shared__ int sh_rk;
  const float* r = raw + b * N;

  // 1. load + max
  float m = -3.0e38f;
  for (int i = 0; i < 16; ++i) {
    const int idx = t + i * 1024;
    const float v = r[idx];
    sraw[idx] = v;
    m = fmaxf(m, v);
  }
  for (int off = 32; off > 0; off >>= 1) m = fmaxf(m, __shfl_down(m, off, 64));
  if (lane == 0) fred[w] = m;
  __syncthreads();
  if (t == 0) {
    float mm = fred[0];
    for (int i = 1; i < 16; ++i) mm = fmaxf(mm, fred[i]);
    shM = mm;
  }
  __syncthreads();
  const float M = shM;

  // 2. sum exp
  float s = 0.f;
  for (int i = 0; i < 16; ++i) s += expf(sraw[t + i * 1024] - M);
  for (int off = 32; off > 0; off >>= 1) s += __shfl_down(s, off, 64);
  if (lane == 0) fred[w] = s;
  __syncthreads();
  if (t == 0) {
    float ss = 0.f;
    for (int i = 0; i < 16; ++i) ss += fred[i];
    shS = ss;
  }
  __syncthreads();
  const float inv = 1.0f / shS;

  // 3. attn write
  for (int i = 0; i < 16; ++i) {
    const int idx = t + i * 1024;
    attn_out[b * N + idx] = expf(sraw[idx] - M) * inv;
  }

  // 4. radix select: threshold key + stable tie count
  uint32_t prefix = 0;
  int rk = N_TOP;
  for (int pass = 3; pass >= 0; --pass) {
    const int sh = pass * 8;
#pragma unroll
    for (int q = 0; q < 4; ++q) whist[w][lane * 4 + q] = 0;
    __syncthreads();
    for (int i = 0; i < 16; ++i) {
      const uint32_t key = f2key(sraw[t + i * 1024]);
      if (pass == 3 || (key >> (sh + 8)) == (prefix >> (sh + 8)))
        atomicAdd(&whist[w][(key >> sh) & 255], 1);
    }
    __syncthreads();
    if (t < 256) {
      int tot = 0;
      for (int ww = 0; ww < 16; ++ww) tot += whist[ww][t];
      ghist[t] = tot;
    }
    __syncthreads();
    if (t == 0) {
      int cum = 0, dsel = 0;
      for (int dgt = 255; dgt >= 0; --dgt) {
        const int h = ghist[dgt];
        if (cum + h >= rk) { dsel = dgt; break; }
        cum += h;
      }
      sh_prefix = prefix | ((uint32_t)dsel << sh);
      sh_rk = rk - cum;
    }
    __syncthreads();
    prefix = sh_prefix;
    rk = sh_rk;
    __syncthreads();
  }
  const uint32_t T = prefix;
  const int tieTake = rk;

  // 5. membership + p-rank + psel lookup + selection (contiguous chunks)
  const int n0 = t * 16;
  int cgt = 0, ceq = 0;
  for (int i = 0; i < 16; ++i) {
    const uint32_t key = f2key(sraw[n0 + i]);
    cgt += (key > T);
    ceq += (key == T);
  }
  const int gbase = scan1024(cgt, wred, t);
  const int ebase = scan1024(ceq, wred, t);
  int grun = gbase, erun = ebase;
  unsigned selmask = 0;
  int csel = 0;
  for (int i = 0; i < 16; ++i) {
    const int n = n0 + i;
    const uint32_t key = f2key(sraw[n]);
    const bool gt = key > T, eq = key == T;
    const bool mem = gt || (eq && erun < tieTake);
    int sel;
    if (mem) {
      sel = 1;
    } else {
      const int members_before = grun + (erun < tieTake ? erun : tieTake);
      const int p = n - members_before;
      sel = psel[b * N_REM + p];
    }
    selmask |= (unsigned)sel << i;
    csel += sel;
    grun += gt;
    erun += eq;
  }
  int q = scan1024(csel, wred, t);
  for (int i = 0; i < 16; ++i) {
    if ((selmask >> i) & 1) {
      const int n = n0 + i;
      sel_ws[b * K_SEL + q] = n;
      out_selidx[b * K_SEL + q] = (float)n;
      ++q;
    }
  }
}

// ---- K4: gather selected feature rows ------------------------------------
__global__ __launch_bounds__(128) void gather_kernel(
    const float* __restrict__ feat, const int* __restrict__ sel_ws,
    float* __restrict__ out_sel) {
  const int qa = blockIdx.x;
  const int b = qa / K_SEL;
  const int n = sel_ws[qa];
  const float4* src =
      reinterpret_cast<const float4*>(feat + (size_t)(b * N + n) * D);
  float4* dst = reinterpret_cast<float4*>(out_sel + (size_t)qa * D);
  dst[threadIdx.x] = src[threadIdx.x];
}

extern "C" void kernel_launch(void* const* d_in, const int* in_sizes, int n_in,
                              void* d_out, int out_size, void* d_ws,
                              size_t ws_size, hipStream_t stream) {
  const float* feat = (const float*)d_in[0];
  const float* WV = (const float*)d_in[1];
  const float* bV = (const float*)d_in[2];
  const float* WU = (const float*)d_in[3];
  const float* bU = (const float*)d_in[4];
  const float* watt = (const float*)d_in[5];
  const float* batt = (const float*)d_in[6];

  float* out = (float*)d_out;
  float* out_selected = out;                      // B*K_SEL*D floats
  float* out_attn = out + (size_t)B * K_SEL * D;  // B*N floats
  float* out_selidx = out_attn + (size_t)B * N;   // B*K_SEL floats

  float* wqf = (float*)d_ws;                  // D/2*H*4 = 262144 floats
  float* raw = wqf + (size_t)(D / 2) * H * 4; // NROWS floats
  int* psel = (int*)(raw + NROWS);            // B*N_REM
  int* sel_ws = psel + B * N_REM;             // B*K_SEL

  wprep_kernel<<<D / 2, 256, 0, stream>>>(WV, WU, wqf);
  rand_select_kernel<<<B, 1024, 0, stream>>>(psel);
  score_kernel<<<NROWS / 32, 256, 0, stream>>>(feat, wqf, bV, bU, watt, batt,
                                               raw);
  select_kernel<<<B, 1024, 0, stream>>>(raw, psel, out_attn, sel_ws,
                                        out_selidx);
  gather_kernel<<<B * K_SEL, 128, 0, stream>>>(feat, sel_ws, out_selected);
}